// Round 12
// baseline (690.622 us; speedup 1.0000x reference)
//
#include <hip/hip_runtime.h>
#include <cstddef>

#define BB   256    // batch = GEMM1 M
#define UU   8      // in_units
#define ISZ  1152   // in_size
#define JJ   10     // out_units
#define DD   16     // out_size
#define JD   (JJ*DD)      // 160
#define K1   (UU*ISZ)     // 9216 ; sgemm k-order: k = i*8+u
#define ICH  16           // i per sgemm block-job
#define NIC  (ISZ/ICH)    // 72 split-K parts
#define GRID 512

typedef short v8s __attribute__((ext_vector_type(8)));   // 8 bf16 in 4 VGPRs
typedef float f4v __attribute__((ext_vector_type(4)));   // mfma accumulator
typedef unsigned short ush;

__device__ __forceinline__ ush f2bf(float f) {
    unsigned int u = __float_as_uint(f);
    unsigned int r = (u + 0x7fffu + ((u >> 16) & 1u)) >> 16;   // RNE
    return (ush)r;
}
__device__ __forceinline__ float bf2f(ush h) {
    return __uint_as_float(((unsigned int)h) << 16);
}
__device__ __forceinline__ float aload(const float* p) {
    return __hip_atomic_load(p, __ATOMIC_RELAXED, __HIP_MEMORY_SCOPE_AGENT);
}

// Contention-free grid barrier: per-block flag stores (parallel, no RMW),
// block-0 scan, single release word. Epochs monotone -> no reset/ABA.
__device__ __forceinline__ void gbar(int* flags, int* rel, int ep) {
    __syncthreads();
    if (threadIdx.x == 0)
        __hip_atomic_store(&flags[blockIdx.x], ep, __ATOMIC_RELEASE, __HIP_MEMORY_SCOPE_AGENT);
    if (blockIdx.x == 0) {
        for (int i = threadIdx.x; i < GRID; i += 256)
            while (__hip_atomic_load(&flags[i], __ATOMIC_ACQUIRE, __HIP_MEMORY_SCOPE_AGENT) < ep)
                __builtin_amdgcn_s_sleep(2);
        __syncthreads();
        if (threadIdx.x == 0)
            __hip_atomic_store(rel, ep, __ATOMIC_RELEASE, __HIP_MEMORY_SCOPE_AGENT);
    }
    if (threadIdx.x == 0)
        while (__hip_atomic_load(rel, __ATOMIC_ACQUIRE, __HIP_MEMORY_SCOPE_AGENT) < ep)
            __builtin_amdgcn_s_sleep(8);
    __syncthreads();
}

union __align__(16) SMem {
    float prep_buf[16][8][65];                        // 33.3 KB (max member)
    struct {
        ush bh[2][16][136];                           // B^T hi [jj][d][k_local]
        ush bl[2][16][136];                           // B^T lo
        float c[2][ICH];
        float redm[4], reds[4];
    } sg;
    float sm[JD];
};

__global__ __launch_bounds__(256, 2) void capsule_persist(
        const float* __restrict__ x, const float* __restrict__ W,
        float* __restrict__ v_out, int* flags, int* rel,
        float* __restrict__ b_ij, float* __restrict__ s_part,
        ush* __restrict__ xsh, ush* __restrict__ xsl,
        ush* __restrict__ xth, ush* __restrict__ xtl,
        ush* __restrict__ vth, ush* __restrict__ vtl) {
    __shared__ SMem smem;
    int bid = blockIdx.x;
    int t = threadIdx.x, lane = t & 63, wv = t >> 6;
    int col = lane & 15, q = lane >> 4;
    int ep = 0;

    // ---- P0: prep x -> xs[i][b*8+u] + xt[u*1152+i][b] (bf16-split); b_ij = 1 ----
    if (bid < 45) b_ij[bid * 256 + t] = 1.0f;         // 45*256 = 11520
    if (bid < 288) {
        int itile = bid % 18, btile = bid / 18;       // 18 i-tiles x 16 b-tiles
        int i0 = itile * 64, b0 = btile * 16;
        for (int rep = 0; rep < 32; ++rep) {
            int row = rep * 4 + wv;                   // 0..127 = (bl,u)
            int bl = row >> 3, u = row & 7;
            smem.prep_buf[bl][u][lane] =
                x[(size_t)(b0 + bl) * K1 + (size_t)u * ISZ + i0 + lane];
        }
        __syncthreads();
        {   // xs[i][b*8+u]
            int half = t >> 7, bl = (t & 127) >> 3, u = t & 7;
            for (int il = half * 32; il < half * 32 + 32; ++il) {
                float v = smem.prep_buf[bl][u][il];
                ush h = f2bf(v);
                size_t o = (size_t)(i0 + il) * 2048 + (size_t)(b0 + bl) * 8 + u;
                xsh[o] = h; xsl[o] = f2bf(v - bf2f(h));
            }
        }
        {   // xt[u*1152+i][b]
            int bl = t & 15, r = t >> 4;
            for (int pass = 0; pass < 32; ++pass) {
                int row = pass * 16 + r;              // 0..511 = (u,il)
                int u = row >> 6, il = row & 63;
                float v = smem.prep_buf[bl][u][il];
                ush h = f2bf(v);
                size_t o = (size_t)(u * ISZ + i0 + il) * BB + b0 + bl;
                xth[o] = h; xtl[o] = f2bf(v - bf2f(h));
            }
        }
    }
    gbar(flags, rel, ++ep);

    for (int it = 0; it < 3; ++it) {
        // ---- P1: sgemm (R11-verified): 360 jobs of 2 j x 16 i ----
        if (bid < 360) {
            int jh = bid % 5, ic = bid / 5;
            int j0 = jh * 2, i0 = ic * ICH;

            if (it == 0) {
                if (t < 2 * ICH) smem.sg.c[t >> 4][t & 15] = 1.0f / 1152.0f;
            } else {
                for (int jj = 0; jj < 2; ++jj) {
                    const float* bp = b_ij + (size_t)(j0 + jj) * ISZ;
                    float m = -1e30f;
                    for (int k = t; k < ISZ; k += 256) m = fmaxf(m, aload(bp + k));
#pragma unroll
                    for (int off = 32; off; off >>= 1) m = fmaxf(m, __shfl_down(m, off, 64));
                    if (lane == 0) smem.sg.redm[wv] = m;
                    __syncthreads();
                    m = fmaxf(fmaxf(smem.sg.redm[0], smem.sg.redm[1]),
                              fmaxf(smem.sg.redm[2], smem.sg.redm[3]));
                    float ss = 0.f;
                    for (int k = t; k < ISZ; k += 256) ss += __expf(aload(bp + k) - m);
#pragma unroll
                    for (int off = 32; off; off >>= 1) ss += __shfl_down(ss, off, 64);
                    if (lane == 0) smem.sg.reds[wv] = ss;
                    __syncthreads();
                    float inv = 1.f / (smem.sg.reds[0] + smem.sg.reds[1]
                                       + smem.sg.reds[2] + smem.sg.reds[3]);
                    if (t < ICH) smem.sg.c[jj][t] = __expf(aload(bp + i0 + t) - m) * inv;
                    __syncthreads();
                }
            }
            __syncthreads();

            for (int slot = t; slot < 512; slot += 256) {   // build B tiles
                int jj = slot >> 8, rem = slot & 255, ii = rem >> 4, d = rem & 15;
                const float* wp = W + (size_t)(i0 + ii) * 1280 + (j0 + jj) * 128 + d * 8;
                float4 wa = *(const float4*)wp;
                float4 wb = *(const float4*)(wp + 4);
                float ci = smem.sg.c[jj][ii];
                float vals[8] = { wa.x * ci, wa.y * ci, wa.z * ci, wa.w * ci,
                                  wb.x * ci, wb.y * ci, wb.z * ci, wb.w * ci };
                v8s hv, lv;
#pragma unroll
                for (int u = 0; u < 8; ++u) {
                    ush h = f2bf(vals[u]);
                    hv[u] = (short)h;
                    lv[u] = (short)f2bf(vals[u] - bf2f(h));
                }
                *(v8s*)&smem.sg.bh[jj][d][ii * 8] = hv;
                *(v8s*)&smem.sg.bl[jj][d][ii * 8] = lv;
            }
            __syncthreads();

            int m_base = wv * 64;
            f4v acc[4][2];
#pragma unroll
            for (int mm = 0; mm < 4; ++mm)
#pragma unroll
                for (int jj = 0; jj < 2; ++jj) acc[mm][jj] = (f4v){0.f, 0.f, 0.f, 0.f};
#pragma unroll
            for (int s = 0; s < 4; ++s) {
                v8s bh0 = *(const v8s*)&smem.sg.bh[0][col][s * 32 + q * 8];
                v8s bl0 = *(const v8s*)&smem.sg.bl[0][col][s * 32 + q * 8];
                v8s bh1 = *(const v8s*)&smem.sg.bh[1][col][s * 32 + q * 8];
                v8s bl1 = *(const v8s*)&smem.sg.bl[1][col][s * 32 + q * 8];
                size_t abase = (size_t)(i0 + s * 4 + q) * 2048;
#pragma unroll
                for (int mm = 0; mm < 4; ++mm) {
                    size_t ao = abase + (size_t)(m_base + mm * 16 + col) * 8;
                    v8s ah = *(const v8s*)(xsh + ao);
                    v8s al = *(const v8s*)(xsl + ao);
                    acc[mm][0] = __builtin_amdgcn_mfma_f32_16x16x32_bf16(ah, bh0, acc[mm][0], 0, 0, 0);
                    acc[mm][0] = __builtin_amdgcn_mfma_f32_16x16x32_bf16(ah, bl0, acc[mm][0], 0, 0, 0);
                    acc[mm][0] = __builtin_amdgcn_mfma_f32_16x16x32_bf16(al, bh0, acc[mm][0], 0, 0, 0);
                    acc[mm][1] = __builtin_amdgcn_mfma_f32_16x16x32_bf16(ah, bh1, acc[mm][1], 0, 0, 0);
                    acc[mm][1] = __builtin_amdgcn_mfma_f32_16x16x32_bf16(ah, bl1, acc[mm][1], 0, 0, 0);
                    acc[mm][1] = __builtin_amdgcn_mfma_f32_16x16x32_bf16(al, bh1, acc[mm][1], 0, 0, 0);
                }
            }
#pragma unroll
            for (int mm = 0; mm < 4; ++mm)
#pragma unroll
                for (int jj = 0; jj < 2; ++jj)
#pragma unroll
                    for (int r = 0; r < 4; ++r)
                        s_part[((size_t)ic * BB + m_base + mm * 16 + q * 4 + r) * JD
                               + (j0 + jj) * DD + col] = acc[mm][jj][r];
        }
        gbar(flags, rel, ++ep);

        // ---- P2: reduce split-K + squash; v_out + vT bf16-split ----
        if (bid < BB) {
            int b = bid;
            if (t < JD) {
                float s = 0.f;
#pragma unroll 8
                for (int p = 0; p < NIC; ++p) s += s_part[((size_t)p * BB + b) * JD + t];
                smem.sm[t] = s;
            }
            __syncthreads();
            if (t < JD) {
                int d = t & 15;
                float msq = 0.f;
#pragma unroll
                for (int j = 0; j < JJ; ++j) { float xx = smem.sm[j * DD + d]; msq += xx * xx; }
                float val = msq / (1.f + msq) * smem.sm[t] * rsqrtf(msq);
                v_out[(size_t)b * JD + t] = val;
                ush h = f2bf(val);
                vth[(size_t)t * BB + b] = h;
                vtl[(size_t)t * BB + b] = f2bf(val - bf2f(h));
            }
        }
        if (it == 2) break;               // final iteration: v_out done
        gbar(flags, rel, ++ep);

        // ---- P3: mgemm (vT @ x, K=256) + agreement epilogue [R7-verified] ----
        for (int job = bid; job < 1440; job += GRID) {
            int wj = job * 4 + wv;        // 5760 wave-jobs
            int mt = wj / 576, nt = wj % 576;
            int m0 = mt * 16, n0 = nt * 16;
            size_t aoff = (size_t)(m0 + col) * BB + q * 8;
            size_t boff = (size_t)(n0 + col) * BB + q * 8;
            f4v acc = {0.f, 0.f, 0.f, 0.f};
#pragma unroll
            for (int s = 0; s < BB / 32; ++s) {
                v8s ah = *(const v8s*)(vth + aoff);
                v8s al = *(const v8s*)(vtl + aoff);
                v8s bh = *(const v8s*)(xth + boff);
                v8s bl = *(const v8s*)(xtl + boff);
                acc = __builtin_amdgcn_mfma_f32_16x16x32_bf16(ah, bh, acc, 0, 0, 0);
                acc = __builtin_amdgcn_mfma_f32_16x16x32_bf16(ah, bl, acc, 0, 0, 0);
                acc = __builtin_amdgcn_mfma_f32_16x16x32_bf16(al, bh, acc, 0, 0, 0);
                aoff += 32; boff += 32;
            }
            int u = nt / 72;
            int i = (nt % 72) * 16 + col;
            const float* Wp = W + (size_t)i * 1280 + mt * 128 + q * 32 + u;
            float p = Wp[0] * acc[0] + Wp[8] * acc[1] + Wp[16] * acc[2] + Wp[24] * acc[3];
            p += __shfl_xor(p, 16, 64);
            p += __shfl_xor(p, 32, 64);
            if (q == 0) atomicAdd(&b_ij[(size_t)mt * ISZ + i], p * (1.0f / 256.0f));
        }
        gbar(flags, rel, ++ep);
    }
}

extern "C" void kernel_launch(void* const* d_in, const int* in_sizes, int n_in,
                              void* d_out, int out_size, void* d_ws, size_t ws_size,
                              hipStream_t stream) {
    const float* x = (const float*)d_in[0];   // (256, 8, 1152)
    const float* W = (const float*)d_in[1];   // (1, 1152, 10, 16, 8)
    float* v_out = (float*)d_out;             // (256, 10, 16, 1)

    int*   flags  = (int*)d_ws;                            // 512 + 512 (rel padded)
    int*   rel    = flags + GRID;
    float* b_ij   = (float*)d_ws + 1024;                   // 11,520 f
    float* s_part = b_ij + ISZ * JJ;                       // 72*256*160 f
    ush* xsh = (ush*)(s_part + (size_t)NIC * BB * JD);     // [1152][2048]
    ush* xsl = xsh + (size_t)ISZ * 2048;
    ush* xth = xsl + (size_t)ISZ * 2048;                   // [9216][256]
    ush* xtl = xth + (size_t)K1 * BB;
    ush* vth = xtl + (size_t)K1 * BB;                      // [160][256]
    ush* vtl = vth + (size_t)JD * BB;

    hipMemsetAsync(flags, 0, 1024 * sizeof(int), stream);  // zero barrier state
    hipLaunchKernelGGL(capsule_persist, dim3(GRID), dim3(256), 0, stream,
                       x, W, v_out, flags, rel, b_ij, s_part,
                       xsh, xsl, xth, xtl, vth, vtl);
}

// Round 13
// 236.298 us; speedup vs baseline: 2.9227x; 2.9227x over previous
//
#include <hip/hip_runtime.h>
#include <cstddef>

#define BB   256    // batch = GEMM1 M
#define UU   8      // in_units
#define ISZ  1152   // in_size
#define JJ   10     // out_units
#define DD   16     // out_size
#define JD   (JJ*DD)      // 160
#define K1   (UU*ISZ)     // 9216 ; sgemm k-order: k = i*8+u
#define ICH  48           // i per sgemm block (3 sub-chunks of 16)
#define NIC  (ISZ/ICH)    // 24

typedef short v8s __attribute__((ext_vector_type(8)));   // 8 bf16 in 4 VGPRs
typedef float f4v __attribute__((ext_vector_type(4)));   // mfma accumulator
typedef unsigned short ush;

__device__ __forceinline__ ush f2bf(float f) {
    unsigned int u = __float_as_uint(f);
    unsigned int r = (u + 0x7fffu + ((u >> 16) & 1u)) >> 16;   // RNE
    return (ush)r;
}
__device__ __forceinline__ float bf2f(ush h) {
    return __uint_as_float(((unsigned int)h) << 16);
}

// ---------------- prep: x -> xs[i][b*8+u] + xt[u*1152+i][b] (bf16-split); b_ij=1; zero s1 ----
__global__ void prep_kernel(const float* __restrict__ x,
                            ush* __restrict__ xsh, ush* __restrict__ xsl,
                            ush* __restrict__ xth, ush* __restrict__ xtl,
                            float* __restrict__ b_ij, float* __restrict__ s_red1) {
    __shared__ float buf[32][8][65];
    int it = blockIdx.x;            // 18 tiles of 64 i
    int bt = blockIdx.y;            // 8 tiles of 32 b
    int i0 = it * 64, b0 = bt * 32;
    int t = threadIdx.x, lane = t & 63, wv = t >> 6;

    int flat = bt * 18 + it;
    if (flat < 45) b_ij[flat * 256 + t] = 1.0f;   // 45*256 = 11520
    else if (flat < 85)                            // zero s_red1 (40960 floats)
        ((float4*)s_red1)[(flat - 45) * 256 + t] = make_float4(0.f, 0.f, 0.f, 0.f);

    for (int rep = 0; rep < 64; ++rep) {
        int row = rep * 4 + wv;     // 0..255 = (bl,u)
        int bl = row >> 3, u = row & 7;
        buf[bl][u][lane] = x[(size_t)(b0 + bl) * K1 + (size_t)u * ISZ + i0 + lane];
    }
    __syncthreads();
    {   // xs[i][b*8+u]
        int bl = t >> 3, u = t & 7;
        for (int il = 0; il < 64; ++il) {
            float v = buf[bl][u][il];
            ush h = f2bf(v);
            size_t o = (size_t)(i0 + il) * 2048 + (size_t)(b0 + bl) * 8 + u;
            xsh[o] = h; xsl[o] = f2bf(v - bf2f(h));
        }
    }
    {   // xt[u*1152+i][b]
        int g = t >> 5, bl = t & 31;
        for (int pass = 0; pass < 64; ++pass) {
            int cu = pass * 8 + g;
            int u = cu >> 6, il = cu & 63;
            float v = buf[bl][u][il];
            ush h = f2bf(v);
            size_t o = (size_t)(u * ISZ + i0 + il) * BB + b0 + bl;
            xth[o] = h; xtl[o] = f2bf(v - bf2f(h));
        }
    }
}

// ---------------- sgemm: atomic-accumulate s_red[jd][b]; fused softmax ----------------
// grid (5 j-pairs, NIC) = 120 blocks, 4 waves x 4 m-tiles x 2 j; 3 sub-chunks of 16 i.
__global__ __launch_bounds__(256, 2) void sgemm_atomic(
        const ush* __restrict__ xsh, const ush* __restrict__ xsl,
        const float* __restrict__ W, const float* __restrict__ b_ij,
        float* __restrict__ s_red, int first) {
    int jh = blockIdx.x, ic = blockIdx.y;
    int j0 = jh * 2, i0 = ic * ICH;
    int t = threadIdx.x, lane = t & 63, wv = t >> 6;
    int col = lane & 15, q = lane >> 4;

    __shared__ __align__(16) ush bh_[2][16][136];   // B^T hi [jj][d][k_local]
    __shared__ __align__(16) ush bl_[2][16][136];   // B^T lo
    __shared__ float c_lds[2][ICH];
    __shared__ float redm[4], reds[4];

    if (first) {
        if (t < 2 * ICH) c_lds[t / ICH][t % ICH] = 1.0f / 1152.0f;
    } else {
        for (int jj = 0; jj < 2; ++jj) {
            const float* bp = b_ij + (size_t)(j0 + jj) * ISZ;
            float m = -1e30f;
            for (int k = t; k < ISZ; k += 256) m = fmaxf(m, bp[k]);
#pragma unroll
            for (int off = 32; off; off >>= 1) m = fmaxf(m, __shfl_down(m, off, 64));
            if (lane == 0) redm[wv] = m;
            __syncthreads();
            m = fmaxf(fmaxf(redm[0], redm[1]), fmaxf(redm[2], redm[3]));
            float ss = 0.f;
            for (int k = t; k < ISZ; k += 256) ss += __expf(bp[k] - m);
#pragma unroll
            for (int off = 32; off; off >>= 1) ss += __shfl_down(ss, off, 64);
            if (lane == 0) reds[wv] = ss;
            __syncthreads();
            float inv = 1.f / (reds[0] + reds[1] + reds[2] + reds[3]);
            if (t < ICH) c_lds[jj][t] = __expf(bp[i0 + t] - m) * inv;
            __syncthreads();
        }
    }

    int m_base = wv * 64;
    f4v acc[4][2];
#pragma unroll
    for (int mm = 0; mm < 4; ++mm)
#pragma unroll
        for (int jj = 0; jj < 2; ++jj) acc[mm][jj] = (f4v){0.f, 0.f, 0.f, 0.f};

    for (int sc = 0; sc < 3; ++sc) {        // 3 sub-chunks of 16 i
        __syncthreads();                    // prior LDS reads done
        for (int slot = t; slot < 512; slot += 256) {   // build B tiles
            int jj = slot >> 8, rem = slot & 255, ii = rem >> 4, d = rem & 15;
            int iG = i0 + sc * 16 + ii;
            const float* wp = W + (size_t)iG * 1280 + (j0 + jj) * 128 + d * 8;
            float4 wa = *(const float4*)wp;
            float4 wb = *(const float4*)(wp + 4);
            float ci = c_lds[jj][sc * 16 + ii];
            float vals[8] = { wa.x * ci, wa.y * ci, wa.z * ci, wa.w * ci,
                              wb.x * ci, wb.y * ci, wb.z * ci, wb.w * ci };
            v8s hv, lv;
#pragma unroll
            for (int u = 0; u < 8; ++u) {
                ush h = f2bf(vals[u]);
                hv[u] = (short)h;
                lv[u] = (short)f2bf(vals[u] - bf2f(h));
            }
            *(v8s*)&bh_[jj][d][ii * 8] = hv;
            *(v8s*)&bl_[jj][d][ii * 8] = lv;
        }
        __syncthreads();
#pragma unroll
        for (int s = 0; s < 4; ++s) {
            v8s bh0 = *(const v8s*)&bh_[0][col][s * 32 + q * 8];
            v8s bl0 = *(const v8s*)&bl_[0][col][s * 32 + q * 8];
            v8s bh1 = *(const v8s*)&bh_[1][col][s * 32 + q * 8];
            v8s bl1 = *(const v8s*)&bl_[1][col][s * 32 + q * 8];
            size_t abase = (size_t)(i0 + sc * 16 + s * 4 + q) * 2048;
#pragma unroll
            for (int mm = 0; mm < 4; ++mm) {
                size_t ao = abase + (size_t)(m_base + mm * 16 + col) * 8;
                v8s ah = *(const v8s*)(xsh + ao);
                v8s al = *(const v8s*)(xsl + ao);
                acc[mm][0] = __builtin_amdgcn_mfma_f32_16x16x32_bf16(ah, bh0, acc[mm][0], 0, 0, 0);
                acc[mm][0] = __builtin_amdgcn_mfma_f32_16x16x32_bf16(ah, bl0, acc[mm][0], 0, 0, 0);
                acc[mm][0] = __builtin_amdgcn_mfma_f32_16x16x32_bf16(al, bh0, acc[mm][0], 0, 0, 0);
                acc[mm][1] = __builtin_amdgcn_mfma_f32_16x16x32_bf16(ah, bh1, acc[mm][1], 0, 0, 0);
                acc[mm][1] = __builtin_amdgcn_mfma_f32_16x16x32_bf16(ah, bl1, acc[mm][1], 0, 0, 0);
                acc[mm][1] = __builtin_amdgcn_mfma_f32_16x16x32_bf16(al, bh1, acc[mm][1], 0, 0, 0);
            }
        }
    }
    // fire-and-forget atomic accumulate: s_red[jd][b]
#pragma unroll
    for (int mm = 0; mm < 4; ++mm)
#pragma unroll
        for (int jj = 0; jj < 2; ++jj)
#pragma unroll
            for (int r = 0; r < 4; ++r)
                atomicAdd(&s_red[(size_t)((j0 + jj) * DD + col) * BB
                                 + m_base + mm * 16 + q * 4 + r], acc[mm][jj][r]);
}

// ---------------- sqmg: squash(s_red) in-block + mgemm + agreement; zero next s_red ----
// grid 144, 4 waves = 4 nt each; loop 10 mt. B-fragments cached in regs across mt.
__global__ __launch_bounds__(256, 2) void sqmg_kernel(
        const ush* __restrict__ xth, const ush* __restrict__ xtl,
        const float* __restrict__ s_red, const float* __restrict__ W,
        float* __restrict__ b_ij, float* __restrict__ s_red_next) {
    int bid = blockIdx.x;
    int t = threadIdx.x, lane = t & 63, wv = t >> 6;
    int col = lane & 15, q = lane >> 4;

    if (bid < 40)   // zero next iteration's s accumulator
        ((float4*)s_red_next)[bid * 256 + t] = make_float4(0.f, 0.f, 0.f, 0.f);

    int nt = bid * 4 + wv;          // 0..575
    int n0 = nt * 16;

    // B fragments (xt slice for this nt), loaded once, reused across 10 mt
    v8s Bh[8], Bl[8];
#pragma unroll
    for (int s = 0; s < 8; ++s) {
        size_t bo = (size_t)(n0 + col) * BB + s * 32 + q * 8;
        Bh[s] = *(const v8s*)(xth + bo);
        Bl[s] = *(const v8s*)(xtl + bo);
    }

    // squash scale g[d] per b (= thread t)
    float msq[16];
#pragma unroll
    for (int d = 0; d < 16; ++d) msq[d] = 0.f;
#pragma unroll 16
    for (int jd = 0; jd < JD; ++jd) {
        float val = s_red[(size_t)jd * BB + t];
        msq[jd & 15] += val * val;
    }
    float g[16];
#pragma unroll
    for (int d = 0; d < 16; ++d)
        g[d] = msq[d] / (1.f + msq[d]) * rsqrtf(msq[d]);

    __shared__ __align__(16) ush avh[16][264];   // v-slice hi [d][b], padded
    __shared__ __align__(16) ush avl[16][264];   // v-slice lo

    int u = nt / 72;
    int i = (nt % 72) * 16 + col;

    for (int mt = 0; mt < JJ; ++mt) {
        __syncthreads();            // prior mt's LDS reads done
#pragma unroll
        for (int d = 0; d < 16; ++d) {
            float val = s_red[(size_t)(mt * DD + d) * BB + t] * g[d];
            ush h = f2bf(val);
            avh[d][t] = h;
            avl[d][t] = f2bf(val - bf2f(h));
        }
        __syncthreads();
        f4v acc = {0.f, 0.f, 0.f, 0.f};
#pragma unroll
        for (int s = 0; s < 8; ++s) {
            v8s ah = *(const v8s*)&avh[col][s * 32 + q * 8];
            v8s al = *(const v8s*)&avl[col][s * 32 + q * 8];
            acc = __builtin_amdgcn_mfma_f32_16x16x32_bf16(ah, Bh[s], acc, 0, 0, 0);
            acc = __builtin_amdgcn_mfma_f32_16x16x32_bf16(ah, Bl[s], acc, 0, 0, 0);
            acc = __builtin_amdgcn_mfma_f32_16x16x32_bf16(al, Bh[s], acc, 0, 0, 0);
        }
        // agreement epilogue [R7-verified]: acc[r] = M[mt*16+q*4+r][n0+col]
        const float* Wp = W + (size_t)i * 1280 + mt * 128 + q * 32 + u;
        float p = Wp[0] * acc[0] + Wp[8] * acc[1] + Wp[16] * acc[2] + Wp[24] * acc[3];
        p += __shfl_xor(p, 16, 64);
        p += __shfl_xor(p, 32, 64);
        if (q == 0) atomicAdd(&b_ij[(size_t)mt * ISZ + i], p * (1.0f / 256.0f));
    }
}

// ---------------- final squash -> d_out ----------------
__global__ void squash_out(const float* __restrict__ s_red, float* __restrict__ v) {
    int b = blockIdx.x, t = threadIdx.x;   // 192, t<160 active
    __shared__ float sm[JD];
    if (t < JD) sm[t] = s_red[(size_t)t * BB + b];
    __syncthreads();
    if (t < JD) {
        int d = t & 15;
        float msq = 0.f;
#pragma unroll
        for (int j = 0; j < JJ; ++j) { float xx = sm[j * DD + d]; msq += xx * xx; }
        v[(size_t)b * JD + t] = msq / (1.f + msq) * sm[t] * rsqrtf(msq);
    }
}

extern "C" void kernel_launch(void* const* d_in, const int* in_sizes, int n_in,
                              void* d_out, int out_size, void* d_ws, size_t ws_size,
                              hipStream_t stream) {
    const float* x = (const float*)d_in[0];   // (256, 8, 1152)
    const float* W = (const float*)d_in[1];   // (1, 1152, 10, 16, 8)
    float* v_out = (float*)d_out;             // (256, 10, 16, 1)

    float* b_ij = (float*)d_ws;                            // 11,520 f
    float* s1   = b_ij + ISZ * JJ;                         // 40,960 f each
    float* s2   = s1 + JD * BB;
    float* s3   = s2 + JD * BB;
    ush* xsh = (ush*)(s3 + JD * BB);                       // [1152][2048]
    ush* xsl = xsh + (size_t)ISZ * 2048;
    ush* xth = xsl + (size_t)ISZ * 2048;                   // [9216][256]
    ush* xtl = xth + (size_t)K1 * BB;

    hipLaunchKernelGGL(prep_kernel, dim3(18, 8), dim3(256), 0, stream,
                       x, xsh, xsl, xth, xtl, b_ij, s1);
    hipLaunchKernelGGL(sgemm_atomic, dim3(5, NIC), dim3(256), 0, stream,
                       xsh, xsl, W, b_ij, s1, 1);
    hipLaunchKernelGGL(sqmg_kernel, dim3(144), dim3(256), 0, stream,
                       xth, xtl, s1, W, b_ij, s2);
    hipLaunchKernelGGL(sgemm_atomic, dim3(5, NIC), dim3(256), 0, stream,
                       xsh, xsl, W, b_ij, s2, 0);
    hipLaunchKernelGGL(sqmg_kernel, dim3(144), dim3(256), 0, stream,
                       xth, xtl, s2, W, b_ij, s3);
    hipLaunchKernelGGL(sgemm_atomic, dim3(5, NIC), dim3(256), 0, stream,
                       xsh, xsl, W, b_ij, s3, 0);
    hipLaunchKernelGGL(squash_out, dim3(BB), dim3(192), 0, stream, s3, v_out);
}